// Round 1
// baseline (135.987 us; speedup 1.0000x reference)
//
#include <hip/hip_runtime.h>

// Where2comm AttenFusion, ego-row-only.
// x: (B=16, N=5, C=64, H*W=25200) f32, out: (B, C, H*W) f32.
// Per pixel p: dot[m] = <x[b,0,:,p], x[b,m,:,p]>/8 ; w = softmax(dot);
// out[b,:,p] = sum_m w[m] * x[b,m,:,p].
// Decomposition: 4 lanes per pixel, 16 channels per lane; dots reduced
// with 2x shfl_xor within the 4-lane group. Single pass, all data in VGPRs.

#define B_ 16
#define N_ 5
#define C_ 64
#define HW_ 25200

__global__ __launch_bounds__(256) void where2comm_atten_kernel(
    const float* __restrict__ x, float* __restrict__ out)
{
    const int tid = blockIdx.x * 256 + threadIdx.x;
    const int pix = tid >> 2;        // global pixel id in [0, B*HW)
    const int q   = tid & 3;         // channel quarter: handles c = q*16 .. q*16+15
    const int b   = pix / HW_;
    const int p   = pix - b * HW_;

    const float* xb = x + (size_t)b * (N_ * C_ * HW_) + (size_t)(q * 16) * HW_ + p;

    // Load this lane's 16 channels of all 5 cav vectors. Fully register-resident.
    float v[N_][16];
#pragma unroll
    for (int m = 0; m < N_; ++m) {
#pragma unroll
        for (int i = 0; i < 16; ++i) {
            v[m][i] = xb[(size_t)(m * C_ + i) * HW_];
        }
    }

    // dot[m] = <ego, v[m]> / sqrt(C)  (ego = v[0]); 4-lane group reduce.
    float w[N_];
#pragma unroll
    for (int m = 0; m < N_; ++m) {
        float d = 0.f;
#pragma unroll
        for (int i = 0; i < 16; ++i) d += v[0][i] * v[m][i];
        d += __shfl_xor(d, 1);
        d += __shfl_xor(d, 2);
        w[m] = d * 0.125f;           // / sqrt(64)
    }

    // softmax over the 5 cavs (replicated identically in all 4 lanes)
    float mx = w[0];
#pragma unroll
    for (int m = 1; m < N_; ++m) mx = fmaxf(mx, w[m]);
    float s = 0.f;
#pragma unroll
    for (int m = 0; m < N_; ++m) { w[m] = __expf(w[m] - mx); s += w[m]; }
    const float inv = 1.0f / s;

    // out[b, q*16+i, p] = sum_m w[m] * v[m][i]
    float* ob = out + (size_t)b * (C_ * HW_) + (size_t)(q * 16) * HW_ + p;
#pragma unroll
    for (int i = 0; i < 16; ++i) {
        float a = 0.f;
#pragma unroll
        for (int m = 0; m < N_; ++m) a += w[m] * v[m][i];
        ob[(size_t)i * HW_] = a * inv;
    }
}

extern "C" void kernel_launch(void* const* d_in, const int* in_sizes, int n_in,
                              void* d_out, int out_size, void* d_ws, size_t ws_size,
                              hipStream_t stream) {
    const float* x = (const float*)d_in[0];
    float* out = (float*)d_out;
    // total threads = B*HW*4 = 16*25200*4 = 1,612,800 = 6300 blocks of 256 exactly
    const int blocks = (B_ * HW_ * 4) / 256;
    where2comm_atten_kernel<<<blocks, 256, 0, stream>>>(x, out);
}

// Round 2
// 124.630 us; speedup vs baseline: 1.0911x; 1.0911x over previous
//
#include <hip/hip_runtime.h>

// Where2comm AttenFusion, ego-row-only, float4-over-pixels version.
// x: (B=16, N=5, C=64, HW=25200) f32; out: (B, C, HW) f32.
// Per pixel p: dot[m] = <x[b,0,:,p], x[b,m,:,p]>/8; w = softmax(dot);
// out[b,:,p] = sum_m w[m]*x[b,m,:,p].
//
// Decomposition: each lane owns 4 consecutive pixels (one float4 per
// channel) x 4 channels x 5 cavs = 80 VGPRs of data. 16 chan-lanes per
// 4-pixel group; dot reduced across lanes with shfl_xor {4,8,16,32}.
// Lane map: l&3 = pixel-group within wave (contiguous 64B per plane),
// l>>2 = chan-lane. All loads/stores are dwordx4 (16 B/lane).

#define B_ 16
#define N_ 5
#define C_ 64
#define HW_ 25200
#define PG_PER_IMG (HW_ / 4)   // 6300, divisible by 4 -> wave never straddles b

typedef float f4 __attribute__((ext_vector_type(4)));

__global__ __launch_bounds__(256) void where2comm_atten_kernel(
    const float* __restrict__ x, float* __restrict__ out)
{
    const int tid = blockIdx.x * 256 + threadIdx.x;
    const int l   = tid & 63;
    const int pg  = (tid >> 6) * 4 + (l & 3);   // global 4-pixel group
    const int cl  = l >> 2;                     // chan-lane 0..15
    const int b   = pg / PG_PER_IMG;
    const int p   = (pg - b * PG_PER_IMG) * 4;  // pixel offset in image (16B-aligned)

    const float* xb = x + (size_t)b * (N_ * C_ * HW_) + (size_t)(cl * 4) * HW_ + p;

    // Load 5 cavs x 4 channels x 4 pixels, all dwordx4.
    f4 v[N_][4];
#pragma unroll
    for (int m = 0; m < N_; ++m)
#pragma unroll
        for (int j = 0; j < 4; ++j)
            v[m][j] = *reinterpret_cast<const f4*>(xb + (size_t)(m * C_ + j) * HW_);

    // Per-pixel partial dots over this lane's 4 channels.
    f4 d[N_];
#pragma unroll
    for (int m = 0; m < N_; ++m) {
        f4 acc = v[0][0] * v[m][0];
#pragma unroll
        for (int j = 1; j < 4; ++j) acc += v[0][j] * v[m][j];
        d[m] = acc;
    }

    // Reduce across the 16 chan-lanes (lane stride 4): masks 4,8,16,32.
#pragma unroll
    for (int mask = 4; mask <= 32; mask <<= 1)
#pragma unroll
        for (int m = 0; m < N_; ++m)
#pragma unroll
            for (int c = 0; c < 4; ++c)
                d[m][c] += __shfl_xor(d[m][c], mask);

    // Softmax over the 5 cavs, per pixel component.
    f4 wgt[N_];
#pragma unroll
    for (int c = 0; c < 4; ++c) {
        float dd[N_];
#pragma unroll
        for (int m = 0; m < N_; ++m) dd[m] = d[m][c] * 0.125f;  // / sqrt(64)
        float mx = dd[0];
#pragma unroll
        for (int m = 1; m < N_; ++m) mx = fmaxf(mx, dd[m]);
        float s = 0.f;
#pragma unroll
        for (int m = 0; m < N_; ++m) { dd[m] = __expf(dd[m] - mx); s += dd[m]; }
        const float inv = 1.0f / s;
#pragma unroll
        for (int m = 0; m < N_; ++m) wgt[m][c] = dd[m] * inv;
    }

    // out[b, cl*4+j, p..p+3] = sum_m wgt[m] * v[m][j]
    float* ob = out + (size_t)b * (C_ * HW_) + (size_t)(cl * 4) * HW_ + p;
#pragma unroll
    for (int j = 0; j < 4; ++j) {
        f4 a = wgt[0] * v[0][j];
#pragma unroll
        for (int m = 1; m < N_; ++m) a += wgt[m] * v[m][j];
        *reinterpret_cast<f4*>(ob + (size_t)j * HW_) = a;
    }
}

extern "C" void kernel_launch(void* const* d_in, const int* in_sizes, int n_in,
                              void* d_out, int out_size, void* d_ws, size_t ws_size,
                              hipStream_t stream) {
    const float* x = (const float*)d_in[0];
    float* out = (float*)d_out;
    // threads = B*HW/4 groups * 16 lanes = 1,612,800 = 6300 blocks of 256 exactly
    const int blocks = (B_ * HW_ / 4 * 16) / 256;
    where2comm_atten_kernel<<<blocks, 256, 0, stream>>>(x, out);
}